// Round 5
// baseline (33378.152 us; speedup 1.0000x reference)
//
#include <hip/hip_runtime.h>
#include <cstdint>
#include <cstddef>

// Problem constants (match reference)
#define N_ITEMS 16384
#define D_STATE 2048
#define D_SEM   1024
#define S_SLOTS 4096
#define DTHRESH 2.0f

#define B_ITEMS 256              // sequential-scan block size
#define NBLK    (N_ITEMS / B_ITEMS)   // 64
#define CHUNK_BLKS 16            // content-GEMM chunking (16 MB buffer)
#define CHUNK_ITEMS (B_ITEMS * CHUNK_BLKS)  // 4096

typedef unsigned long long u64;
typedef unsigned int u32;

// ---------------------------------------------------------------------------
// Content GEMM: C[i,j] = sum_d A[i,d]*W[j,d] + b[j].  64x64 tile, K=2048.
// ---------------------------------------------------------------------------
__global__ __launch_bounds__(256)
void gemm_kernel(const float* __restrict__ A, const float* __restrict__ W,
                 const float* __restrict__ bias, float* __restrict__ C) {
  __shared__ float As[16][68];
  __shared__ float Bs[16][68];
  const int t = threadIdx.x;
  const int ty = t >> 4, tx = t & 15;
  const int i0 = blockIdx.x * 64, j0 = blockIdx.y * 64;
  const int lrow = t >> 2, lcol = (t & 3) << 2;
  float acc[4][4] = {{0.f}};
  const float* ap = A + (size_t)(i0 + lrow) * D_STATE + lcol;
  const float* wp = W + (size_t)(j0 + lrow) * D_STATE + lcol;
  for (int k0 = 0; k0 < D_STATE; k0 += 16) {
    float4 av = *(const float4*)(ap + k0);
    float4 wv = *(const float4*)(wp + k0);
    __syncthreads();
    As[lcol + 0][lrow] = av.x; As[lcol + 1][lrow] = av.y;
    As[lcol + 2][lrow] = av.z; As[lcol + 3][lrow] = av.w;
    Bs[lcol + 0][lrow] = wv.x; Bs[lcol + 1][lrow] = wv.y;
    Bs[lcol + 2][lrow] = wv.z; Bs[lcol + 3][lrow] = wv.w;
    __syncthreads();
#pragma unroll
    for (int kk = 0; kk < 16; kk++) {
      float a[4], b[4];
#pragma unroll
      for (int y = 0; y < 4; y++) a[y] = As[kk][ty * 4 + y];
#pragma unroll
      for (int x = 0; x < 4; x++) b[x] = Bs[kk][tx * 4 + x];
#pragma unroll
      for (int y = 0; y < 4; y++)
#pragma unroll
        for (int x = 0; x < 4; x++) acc[y][x] = fmaf(a[y], b[x], acc[y][x]);
    }
  }
#pragma unroll
  for (int y = 0; y < 4; y++)
#pragma unroll
    for (int x = 0; x < 4; x++) {
      const int col = j0 + tx * 4 + x;
      C[(size_t)(i0 + ty * 4 + y) * D_SEM + col] = acc[y][x] + bias[col];
    }
}

// ---------------------------------------------------------------------------
// Per-chunk block-diagonal Gram: G[z][i][j] = c_i . c_j within block z.
// grid (4,4,CHUNK_BLKS), 64x64 tiles, K=1024.
// ---------------------------------------------------------------------------
__global__ __launch_bounds__(256)
void gram_kernel(const float* __restrict__ Cc, float* __restrict__ G) {
  const int z = blockIdx.z;
  const float* A = Cc + (size_t)z * B_ITEMS * D_SEM;
  __shared__ float As[16][68];
  __shared__ float Bs[16][68];
  const int t = threadIdx.x;
  const int ty = t >> 4, tx = t & 15;
  const int i0 = blockIdx.x * 64, j0 = blockIdx.y * 64;
  const int lrow = t >> 2, lcol = (t & 3) << 2;
  float acc[4][4] = {{0.f}};
  const float* ap = A + (size_t)(i0 + lrow) * D_SEM + lcol;
  const float* wp = A + (size_t)(j0 + lrow) * D_SEM + lcol;
  for (int k0 = 0; k0 < D_SEM; k0 += 16) {
    float4 av = *(const float4*)(ap + k0);
    float4 wv = *(const float4*)(wp + k0);
    __syncthreads();
    As[lcol + 0][lrow] = av.x; As[lcol + 1][lrow] = av.y;
    As[lcol + 2][lrow] = av.z; As[lcol + 3][lrow] = av.w;
    Bs[lcol + 0][lrow] = wv.x; Bs[lcol + 1][lrow] = wv.y;
    Bs[lcol + 2][lrow] = wv.z; Bs[lcol + 3][lrow] = wv.w;
    __syncthreads();
#pragma unroll
    for (int kk = 0; kk < 16; kk++) {
      float a[4], b[4];
#pragma unroll
      for (int y = 0; y < 4; y++) a[y] = As[kk][ty * 4 + y];
#pragma unroll
      for (int x = 0; x < 4; x++) b[x] = Bs[kk][tx * 4 + x];
#pragma unroll
      for (int y = 0; y < 4; y++)
#pragma unroll
        for (int x = 0; x < 4; x++) acc[y][x] = fmaf(a[y], b[x], acc[y][x]);
    }
  }
  float* Gz = G + (size_t)z * B_ITEMS * B_ITEMS;
#pragma unroll
  for (int y = 0; y < 4; y++)
#pragma unroll
    for (int x = 0; x < 4; x++)
      Gz[(size_t)(i0 + ty * 4 + y) * B_ITEMS + j0 + tx * 4 + x] = acc[y][x];
}

// ---------------------------------------------------------------------------
// Per-block dot-product matrix: P0[i][s] = c_i . t_s(block start).  Read-only
// in the scan.  Tiles past the max-possible-valid limit are zero-filled
// (finite; invalid slots are masked by n_reg=+inf in the scan).  grid (4,64).
// ---------------------------------------------------------------------------
__global__ __launch_bounds__(256)
void pgemm_kernel(const float* __restrict__ A,   // content block 256 x 1024
                  const float* __restrict__ T,   // traces (= out) 4096 x 1024
                  float* __restrict__ P,
                  const int* __restrict__ state) {
  const int limit = min(state[0] + B_ITEMS, S_SLOTS);
  const int j0 = blockIdx.y * 64;
  const int i0 = blockIdx.x * 64;
  const int t = threadIdx.x;
  const int ty = t >> 4, tx = t & 15;
  if (j0 >= limit) {
    const float4 z = {0.f, 0.f, 0.f, 0.f};
    const int col = j0 + tx * 4;
#pragma unroll
    for (int y = 0; y < 4; y++)
      *(float4*)(P + (size_t)(i0 + ty * 4 + y) * S_SLOTS + col) = z;
    return;
  }
  __shared__ float As[16][68];
  __shared__ float Bs[16][68];
  const int lrow = t >> 2, lcol = (t & 3) << 2;
  float acc[4][4] = {{0.f}};
  const float* ap = A + (size_t)(i0 + lrow) * D_SEM + lcol;
  const float* wp = T + (size_t)(j0 + lrow) * D_SEM + lcol;
  for (int k0 = 0; k0 < D_SEM; k0 += 16) {
    float4 av = *(const float4*)(ap + k0);
    float4 wv = *(const float4*)(wp + k0);
    __syncthreads();
    As[lcol + 0][lrow] = av.x; As[lcol + 1][lrow] = av.y;
    As[lcol + 2][lrow] = av.z; As[lcol + 3][lrow] = av.w;
    Bs[lcol + 0][lrow] = wv.x; Bs[lcol + 1][lrow] = wv.y;
    Bs[lcol + 2][lrow] = wv.z; Bs[lcol + 3][lrow] = wv.w;
    __syncthreads();
#pragma unroll
    for (int kk = 0; kk < 16; kk++) {
      float a[4], b[4];
#pragma unroll
      for (int y = 0; y < 4; y++) a[y] = As[kk][ty * 4 + y];
#pragma unroll
      for (int x = 0; x < 4; x++) b[x] = Bs[kk][tx * 4 + x];
#pragma unroll
      for (int y = 0; y < 4; y++)
#pragma unroll
        for (int x = 0; x < 4; x++) acc[y][x] = fmaf(a[y], b[x], acc[y][x]);
    }
  }
#pragma unroll
  for (int y = 0; y < 4; y++)
#pragma unroll
    for (int x = 0; x < 4; x++)
      P[(size_t)(i0 + ty * 4 + y) * S_SLOTS + j0 + tx * 4 + x] = acc[y][x];
}

// ---------------------------------------------------------------------------
// init: copy traces0 -> out (working traces), n_g[s] = ||t_s||^2, reset state.
// ---------------------------------------------------------------------------
__global__ __launch_bounds__(256)
void init_kernel(const float* __restrict__ traces0, float* __restrict__ out,
                 float* __restrict__ n_g, int* __restrict__ state) {
  __shared__ float wsum[4];
  const int s = blockIdx.x, t = threadIdx.x;
  const int lane = t & 63, wave = t >> 6;
  float4 v = *(const float4*)(traces0 + (size_t)s * D_SEM + 4 * t);
  *(float4*)(out + (size_t)s * D_SEM + 4 * t) = v;
  float nn = v.x * v.x + v.y * v.y + v.z * v.z + v.w * v.w;
#pragma unroll
  for (int o = 32; o; o >>= 1) nn += __shfl_down(nn, o, 64);
  if (lane == 0) wsum[wave] = nn;
  __syncthreads();
  if (t == 0) n_g[s] = wsum[0] + wsum[1] + wsum[2] + wsum[3];
  if (s == 0 && t == 0) { state[0] = 0; state[1] = 0; }
}

// ---------------------------------------------------------------------------
// DPP wave64 min (f32): row_shr 1/2/4/8 then row_bcast15 (rows 1,3) and
// row_bcast31 (rows 2,3); lane 63 holds the wave min; readlane broadcasts.
// ---------------------------------------------------------------------------
__device__ __forceinline__ float wave_min_f32(float x) {
  int xi = __float_as_int(x), y;
  y = __builtin_amdgcn_update_dpp(xi, xi, 0x111, 0xF, 0xF, false);  // row_shr:1
  x = fminf(x, __int_as_float(y)); xi = __float_as_int(x);
  y = __builtin_amdgcn_update_dpp(xi, xi, 0x112, 0xF, 0xF, false);  // row_shr:2
  x = fminf(x, __int_as_float(y)); xi = __float_as_int(x);
  y = __builtin_amdgcn_update_dpp(xi, xi, 0x114, 0xF, 0xF, false);  // row_shr:4
  x = fminf(x, __int_as_float(y)); xi = __float_as_int(x);
  y = __builtin_amdgcn_update_dpp(xi, xi, 0x118, 0xF, 0xF, false);  // row_shr:8
  x = fminf(x, __int_as_float(y)); xi = __float_as_int(x);
  y = __builtin_amdgcn_update_dpp(xi, xi, 0x142, 0xA, 0xF, false);  // row_bcast:15
  x = fminf(x, __int_as_float(y)); xi = __float_as_int(x);
  y = __builtin_amdgcn_update_dpp(xi, xi, 0x143, 0xC, 0xF, false);  // row_bcast:31
  x = fminf(x, __int_as_float(y)); xi = __float_as_int(x);
  return __int_as_float(__builtin_amdgcn_readlane(xi, 63));
}

// ---------------------------------------------------------------------------
// Sequential scan, one WG, 256 thr.  Thread t owns slots [16t,16t+16).
// P0 READ-ONLY; trace state as t_s = alpha_s*t_s0 + sum coeff_j*c_j (entry j
// owned by thread j).  Register window is ONLY p_cur (row I); row I+1 enters
// at the end of step I: scatter (pre-barrier, coeffs S_{I-1}) targets row I+1,
// the slot-I owner folds decision I into its cv entry post-barrier, then
// p_cur = alpha*raw + cv.  f32 argmin (DPP + ballot), u64 only at the 4-wave
// partials.  One barrier/step; no global stores in the loop.
// ---------------------------------------------------------------------------
#define CORR_SZ 4352   // 4096 + 4096/16 (stride-17 swizzle)
#define SWZ(s) ((s) + ((s) >> 4))

__global__ __launch_bounds__(256, 1)
void scan_kernel(const float* __restrict__ P, const float* __restrict__ Gb,
                 const float* __restrict__ rewards, const float* __restrict__ n_g,
                 int* __restrict__ state, u64* __restrict__ decs) {
  __shared__ float corr0[CORR_SZ];
  __shared__ float corr1[CORR_SZ];
  __shared__ u64 partials[2][4];
  const int t = threadIdx.x;          // 0..255
  const int lane = t & 63, wave = t >> 6;
  const int s_base = t << 4;
  const int c_base = 17 * t;          // SWZ(s_base + k) == c_base + k

  int num = state[0];
  int ptr = state[1];

  for (int s = t; s < CORR_SZ; s += 256) { corr0[s] = 0.f; corr1[s] = 0.f; }

  // per-slot ||t_s||^2 in owner registers; +inf marks invalid
  float n_reg[16];
#pragma unroll
  for (int k = 0; k < 16; k += 4) {
    float4 nv = *(const float4*)(n_g + s_base + k);
    n_reg[k + 0] = (s_base + k + 0 < num) ? nv.x : __uint_as_float(0x7F800000u);
    n_reg[k + 1] = (s_base + k + 1 < num) ? nv.y : __uint_as_float(0x7F800000u);
    n_reg[k + 2] = (s_base + k + 2 < num) ? nv.z : __uint_as_float(0x7F800000u);
    n_reg[k + 3] = (s_base + k + 3 < num) ? nv.w : __uint_as_float(0x7F800000u);
  }
  float alpha_r[16];
#pragma unroll
  for (int k = 0; k < 16; k++) alpha_r[k] = 1.f;

  // p_cur = row 0 (fully corrected at loop entry)
  float p_cur[16];
#pragma unroll
  for (int k = 0; k < 16; k += 4) {
    float4 v0 = *(const float4*)(P + s_base + k);
    p_cur[k] = v0.x; p_cur[k + 1] = v0.y; p_cur[k + 2] = v0.z; p_cur[k + 3] = v0.w;
  }

  // raw ping-pong: buffer A holds row 1 + G[1][t] initially
  float raw_a[16], raw_b[16];
  float gc_a, gc_b;
  {
    const float* rp = P + (size_t)S_SLOTS + s_base;
#pragma unroll
    for (int k = 0; k < 16; k += 4) {
      float4 v = *(const float4*)(rp + k);
      raw_a[k] = v.x; raw_a[k + 1] = v.y; raw_a[k + 2] = v.z; raw_a[k + 3] = v.w;
    }
    gc_a = Gb[(size_t)B_ITEMS + t];
    gc_b = 0.f;
#pragma unroll
    for (int k = 0; k < 16; k++) raw_b[k] = 0.f;
  }

  float gi = Gb[0];          // G[i][i]
  float ri = rewards[0];

  int my_cslot = -1; float my_coeff = 0.f;   // thread t's decision entry
  u32 my_slot = 0; float my_lr = 0.f;        // decision latch for decs[]

  __syncthreads();   // corr zero-init visible

#define OWNFIX(K, I) { const float nold = n_reg[K]; \
    if (upd) { \
      n_reg[K] = omr * omr * nold + 2.0f * lr * omr * p_cur[K] + lr * lr * gi; \
      alpha_r[K] = __fmul_rn(alpha_r[K], omr); \
      if ((I) + 1 < B_ITEMS) cv[K] = fmaf(omr, cv[K], __fmul_rn(lr, g1)); \
    } else { n_reg[K] = gi; alpha_r[K] = 0.f; \
      if ((I) + 1 < B_ITEMS) cv[K] = g1; } }

#define SCAN_STEP(I, CBUF, RAWC, GCC, RAWN, GCN) { \
    /* TOP: prefetch raw row I+2 + G[I+2][t]; uniforms for this/next step */ \
    if ((I) + 2 < B_ITEMS) { \
      const float* rp = P + (size_t)((I) + 2) * S_SLOTS + s_base; \
      _Pragma("unroll") \
      for (int k = 0; k < 16; k += 4) { \
        float4 v = *(const float4*)(rp + k); \
        RAWN[k] = v.x; RAWN[k + 1] = v.y; RAWN[k + 2] = v.z; RAWN[k + 3] = v.w; \
      } \
      GCN = Gb[(size_t)((I) + 2) * B_ITEMS + t]; \
    } \
    float gi_n = 0.f, ri_n = 0.f, g1 = 0.f; \
    if ((I) + 1 < B_ITEMS) { \
      gi_n = Gb[(size_t)((I) + 1) * B_ITEMS + (I) + 1]; \
      ri_n = rewards[(I) + 1]; \
      g1   = Gb[(size_t)(I) * B_ITEMS + (I) + 1]; \
    } \
    /* SCATTER for entering row I+1 (coeffs S_{I-1}) */ \
    if ((I) + 1 < B_ITEMS && my_coeff != 0.f) \
      atomicAdd(&CBUF[SWZ(my_cslot)], __fmul_rn(my_coeff, GCC)); \
    /* KEYS: f32 d2 per owned slot; local min + lowest-index resolve */ \
    float d2[16]; \
    _Pragma("unroll") \
    for (int k = 0; k < 16; k++) { \
      const float v = fmaf(-2.0f, p_cur[k], n_reg[k] + gi); \
      d2[k] = (v > 0.f) ? v : 0.f; \
    } \
    float dloc = d2[0]; \
    _Pragma("unroll") \
    for (int k = 1; k < 16; k++) dloc = fminf(dloc, d2[k]); \
    u32 iloc = 0; \
    _Pragma("unroll") \
    for (int k = 15; k >= 1; k--) if (d2[k] == dloc) iloc = (u32)k; \
    const u32 sloc = (u32)s_base + iloc; \
    /* wave min via DPP + ballot (lowest lane, exact tie-break) */ \
    const float dmin = wave_min_f32(dloc); \
    const u64 bmask = __ballot(dloc == dmin); \
    const int bl = __ffsll((unsigned long long)bmask) - 1; \
    const u32 swave = (u32)__builtin_amdgcn_readlane((int)sloc, bl); \
    if (lane == 0) \
      partials[(I) & 1][wave] = ((u64)__float_as_uint(dmin) << 32) | swave; \
    asm volatile("s_waitcnt lgkmcnt(0)" ::: "memory"); \
    __builtin_amdgcn_s_barrier(); \
    __builtin_amdgcn_sched_barrier(0); \
    /* DEC: redundant decision; read own corr slice */ \
    u64 bk = partials[(I) & 1][0]; \
    { u64 v = partials[(I) & 1][1]; if (v < bk) bk = v; \
      v = partials[(I) & 1][2]; if (v < bk) bk = v; \
      v = partials[(I) & 1][3]; if (v < bk) bk = v; } \
    float cv[16]; \
    if ((I) + 1 < B_ITEMS) { \
      _Pragma("unroll") \
      for (int k = 0; k < 16; k++) cv[k] = CBUF[c_base + k]; \
    } else { \
      _Pragma("unroll") \
      for (int k = 0; k < 16; k++) cv[k] = 0.f; \
    } \
    const float d2b = __uint_as_float((u32)(bk >> 32)); \
    const int nslot = (int)(u32)bk; \
    const bool upd = (num > 0) && (d2b < 4.0f); \
    const float lr = __fmul_rn(0.01f, __fadd_rn(1.0f, fabsf(ri))); \
    const int slot = upd ? nslot : ptr; \
    const float omr = 1.0f - lr; \
    if (!upd) { num = min(num + 1, S_SLOTS); ptr = (ptr + 1) & (S_SLOTS - 1); } \
    if ((I) == t) { my_slot = (u32)slot | (upd ? 0x80000000u : 0u); my_lr = lr; } \
    if (my_cslot == slot) my_coeff = upd ? __fmul_rn(my_coeff, omr) : 0.f; \
    if ((I) == t) { my_cslot = slot; my_coeff = upd ? lr : 1.f; } \
    /* owner: n/alpha recurrence + cv fix for decision I */ \
    if ((slot >> 4) == t) { \
      switch (slot & 15) { \
        case 0:  OWNFIX(0,  I) break; case 1:  OWNFIX(1,  I) break; \
        case 2:  OWNFIX(2,  I) break; case 3:  OWNFIX(3,  I) break; \
        case 4:  OWNFIX(4,  I) break; case 5:  OWNFIX(5,  I) break; \
        case 6:  OWNFIX(6,  I) break; case 7:  OWNFIX(7,  I) break; \
        case 8:  OWNFIX(8,  I) break; case 9:  OWNFIX(9,  I) break; \
        case 10: OWNFIX(10, I) break; case 11: OWNFIX(11, I) break; \
        case 12: OWNFIX(12, I) break; case 13: OWNFIX(13, I) break; \
        case 14: OWNFIX(14, I) break; default: OWNFIX(15, I) break; \
      } \
    } \
    /* ENTER row I+1: p_cur = alpha*raw + cv; zero own corr entries */ \
    if ((I) + 1 < B_ITEMS) { \
      _Pragma("unroll") \
      for (int k = 0; k < 16; k++) { \
        p_cur[k] = fmaf(alpha_r[k], RAWC[k], cv[k]); \
        CBUF[c_base + k] = 0.f; \
      } \
    } \
    gi = gi_n; ri = ri_n; \
  }

  for (int i = 0; i < B_ITEMS; i += 2) {
    SCAN_STEP(i,     corr0, raw_a, gc_a, raw_b, gc_b)
    SCAN_STEP(i + 1, corr1, raw_b, gc_b, raw_a, gc_a)
  }
#undef SCAN_STEP
#undef OWNFIX

  if (t == 0) { state[0] = num; state[1] = ptr; }
  decs[t] = ((u64)__float_as_uint(my_lr) << 32) | (u64)my_slot;
}

// ---------------------------------------------------------------------------
// apply: materialize the block's trace mutations. WG j owns slot_j iff step j
// is the LAST step touching it. Composition: t = alpha*t_snap + sum beta_j c_j.
// Recomputes exact ||t||^2 -> n_g (bounds numeric drift to one block).
// ---------------------------------------------------------------------------
__global__ __launch_bounds__(256)
void apply_kernel(const float* __restrict__ content,  // block 256 x 1024
                  const u64* __restrict__ decs,       // 256 decisions
                  float* __restrict__ traces,         // = out
                  float* __restrict__ n_g) {
  __shared__ u32 aslot[B_ITEMS];
  __shared__ float alr[B_ITEMS];
  __shared__ float betas[B_ITEMS];
  __shared__ int notowner;
  __shared__ float wsum[4];
  const int t = threadIdx.x, j = blockIdx.x;
  const int lane = t & 63, wave = t >> 6;
  const u64 d = decs[t];
  aslot[t] = (u32)(d & 0xFFFFFFFFull);
  alr[t] = __uint_as_float((u32)(d >> 32));
  if (t == 0) notowner = 0;
  __syncthreads();
  const u32 myslot = aslot[j] & 0x7FFFFFFFu;
  if (t > j && (aslot[t] & 0x7FFFFFFFu) == myslot) notowner = 1;
  __syncthreads();
  if (notowner) return;

  float alpha = 1.f, beta = 0.f;
  for (int k = 0; k < B_ITEMS; k++) {
    const u32 a = aslot[k];
    if ((a & 0x7FFFFFFFu) == myslot) {
      const float lr = alr[k];
      if (a & 0x80000000u) {           // update
        const float om = 1.f - lr;
        alpha *= om; beta *= om;
        if (t == k) beta += lr;
      } else {                         // insert
        alpha = 0.f; beta = (t == k) ? 1.f : 0.f;
      }
    }
  }
  betas[t] = beta;
  __syncthreads();

  float4 v = *(const float4*)(traces + (size_t)myslot * D_SEM + 4 * t);
  v.x *= alpha; v.y *= alpha; v.z *= alpha; v.w *= alpha;
  for (int k = 0; k < B_ITEMS; k++) {
    if ((aslot[k] & 0x7FFFFFFFu) == myslot) {
      const float bk = betas[k];
      const float4 c = *(const float4*)(content + (size_t)k * D_SEM + 4 * t);
      v.x = fmaf(bk, c.x, v.x); v.y = fmaf(bk, c.y, v.y);
      v.z = fmaf(bk, c.z, v.z); v.w = fmaf(bk, c.w, v.w);
    }
  }
  *(float4*)(traces + (size_t)myslot * D_SEM + 4 * t) = v;
  float nn = v.x * v.x + v.y * v.y + v.z * v.z + v.w * v.w;
#pragma unroll
  for (int o = 32; o; o >>= 1) nn += __shfl_down(nn, o, 64);
  if (lane == 0) wsum[wave] = nn;
  __syncthreads();
  if (t == 0) n_g[myslot] = wsum[0] + wsum[1] + wsum[2] + wsum[3];
}

// ---------------------------------------------------------------------------
// finalize: parallel strengths replay via two-pass LDS histogram.
// Per slot: final strength = 1 + (#updates after last insert) if ever
// inserted, else strengths0 + #updates.  Then masked mean + scalars.
// ---------------------------------------------------------------------------
__global__ __launch_bounds__(256)
void finalize_kernel(const float* __restrict__ strengths0,
                     const u64* __restrict__ decs,
                     const int* __restrict__ state, float* __restrict__ out) {
  __shared__ int last_ins[S_SLOTS];
  __shared__ int cnt[S_SLOTS];
  __shared__ float wsum[4];
  const int t = threadIdx.x, lane = t & 63, wave = t >> 6;
  for (int s = t; s < S_SLOTS; s += 256) { last_ins[s] = -1; cnt[s] = 0; }
  __syncthreads();
  // pass 1: last insert index per slot
  for (int k = t; k < N_ITEMS; k += 256) {
    const u32 dd = (u32)(decs[k] & 0xFFFFFFFFull);
    if (!(dd & 0x80000000u)) atomicMax(&last_ins[(int)dd], k);
  }
  __syncthreads();
  // pass 2: count updates after the last insert
  for (int k = t; k < N_ITEMS; k += 256) {
    const u32 dd = (u32)(decs[k] & 0xFFFFFFFFull);
    const int slot = (int)(dd & 0x7FFFFFFFu);
    if ((dd & 0x80000000u) && k > last_ins[slot]) atomicAdd(&cnt[slot], 1);
  }
  __syncthreads();
  const int num = state[0];
  float* outs = out + (size_t)S_SLOTS * D_SEM;
  float lsum = 0.f;
  for (int s = t; s < S_SLOTS; s += 256) {
    const float base = (last_ins[s] >= 0) ? 1.f : strengths0[s];
    const float v = base + (float)cnt[s];
    outs[s] = v;
    if (s < num) lsum += v;
  }
#pragma unroll
  for (int o = 32; o; o >>= 1) lsum += __shfl_down(lsum, o, 64);
  if (lane == 0) wsum[wave] = lsum;
  __syncthreads();
  if (t == 0) {
    const float total = wsum[0] + wsum[1] + wsum[2] + wsum[3];
    float denom = (float)num;
    if (denom < 1.f) denom = 1.f;
    outs[S_SLOTS + 0] = (float)num;
    outs[S_SLOTS + 1] = (float)N_ITEMS;
    outs[S_SLOTS + 2] = (num > 0) ? (total / denom) : 0.f;
  }
}

// ---------------------------------------------------------------------------
extern "C" void kernel_launch(void* const* d_in, const int* in_sizes, int n_in,
                              void* d_out, int out_size, void* d_ws, size_t ws_size,
                              hipStream_t stream) {
  const float* states  = (const float*)d_in[0];
  const float* rewards = (const float*)d_in[1];
  const float* W       = (const float*)d_in[2];
  const float* bias    = (const float*)d_in[3];
  const float* traces0 = (const float*)d_in[4];
  const float* str0    = (const float*)d_in[5];
  float* out = (float*)d_out;   // traces live here (working + final)

  // ws layout (~24.5 MB): content chunk 16MB | P 4MB | Gram 4MB | n_g | decs | state
  char* p = (char*)d_ws;
  float* cbuf = (float*)p;                 p += (size_t)CHUNK_ITEMS * D_SEM * 4;
  float* P    = (float*)p;                 p += (size_t)B_ITEMS * S_SLOTS * 4;
  float* Gb   = (float*)p;                 p += (size_t)CHUNK_BLKS * B_ITEMS * B_ITEMS * 4;
  float* n_g  = (float*)p;                 p += (size_t)S_SLOTS * 4;
  u64*   decs = (u64*)p;                   p += (size_t)N_ITEMS * 8;
  int*   state = (int*)p;

  init_kernel<<<S_SLOTS, 256, 0, stream>>>(traces0, out, n_g, state);

  for (int c = 0; c < N_ITEMS / CHUNK_ITEMS; c++) {
    gemm_kernel<<<dim3(CHUNK_ITEMS / 64, D_SEM / 64), 256, 0, stream>>>(
        states + (size_t)c * CHUNK_ITEMS * D_STATE, W, bias, cbuf);
    gram_kernel<<<dim3(4, 4, CHUNK_BLKS), 256, 0, stream>>>(cbuf, Gb);
    for (int bb = 0; bb < CHUNK_BLKS; bb++) {
      const int b = c * CHUNK_BLKS + bb;
      const float* cblk = cbuf + (size_t)bb * B_ITEMS * D_SEM;
      const float* Gblk = Gb + (size_t)bb * B_ITEMS * B_ITEMS;
      pgemm_kernel<<<dim3(4, S_SLOTS / 64), 256, 0, stream>>>(cblk, out, P, state);
      scan_kernel<<<1, 256, 0, stream>>>(P, Gblk, rewards + (size_t)b * B_ITEMS,
                                         n_g, state, decs + (size_t)b * B_ITEMS);
      apply_kernel<<<B_ITEMS, 256, 0, stream>>>(cblk, decs + (size_t)b * B_ITEMS,
                                                out, n_g);
    }
  }
  finalize_kernel<<<1, 256, 0, stream>>>(str0, decs, state, out);
}

// Round 6
// 32041.043 us; speedup vs baseline: 1.0417x; 1.0417x over previous
//
#include <hip/hip_runtime.h>
#include <cstdint>
#include <cstddef>

// Problem constants (match reference)
#define N_ITEMS 16384
#define D_STATE 2048
#define D_SEM   1024
#define S_SLOTS 4096
#define DTHRESH 2.0f

#define B_ITEMS 256              // sequential-scan block size
#define NBLK    (N_ITEMS / B_ITEMS)   // 64
#define CHUNK_BLKS 16            // content-GEMM chunking (16 MB buffer)
#define CHUNK_ITEMS (B_ITEMS * CHUNK_BLKS)  // 4096

typedef unsigned long long u64;
typedef unsigned int u32;

// ---------------------------------------------------------------------------
// Content GEMM: C[i,j] = sum_d A[i,d]*W[j,d] + b[j].  64x64 tile, K=2048.
// ---------------------------------------------------------------------------
__global__ __launch_bounds__(256)
void gemm_kernel(const float* __restrict__ A, const float* __restrict__ W,
                 const float* __restrict__ bias, float* __restrict__ C) {
  __shared__ float As[16][68];
  __shared__ float Bs[16][68];
  const int t = threadIdx.x;
  const int ty = t >> 4, tx = t & 15;
  const int i0 = blockIdx.x * 64, j0 = blockIdx.y * 64;
  const int lrow = t >> 2, lcol = (t & 3) << 2;
  float acc[4][4] = {{0.f}};
  const float* ap = A + (size_t)(i0 + lrow) * D_STATE + lcol;
  const float* wp = W + (size_t)(j0 + lrow) * D_STATE + lcol;
  for (int k0 = 0; k0 < D_STATE; k0 += 16) {
    float4 av = *(const float4*)(ap + k0);
    float4 wv = *(const float4*)(wp + k0);
    __syncthreads();
    As[lcol + 0][lrow] = av.x; As[lcol + 1][lrow] = av.y;
    As[lcol + 2][lrow] = av.z; As[lcol + 3][lrow] = av.w;
    Bs[lcol + 0][lrow] = wv.x; Bs[lcol + 1][lrow] = wv.y;
    Bs[lcol + 2][lrow] = wv.z; Bs[lcol + 3][lrow] = wv.w;
    __syncthreads();
#pragma unroll
    for (int kk = 0; kk < 16; kk++) {
      float a[4], b[4];
#pragma unroll
      for (int y = 0; y < 4; y++) a[y] = As[kk][ty * 4 + y];
#pragma unroll
      for (int x = 0; x < 4; x++) b[x] = Bs[kk][tx * 4 + x];
#pragma unroll
      for (int y = 0; y < 4; y++)
#pragma unroll
        for (int x = 0; x < 4; x++) acc[y][x] = fmaf(a[y], b[x], acc[y][x]);
    }
  }
#pragma unroll
  for (int y = 0; y < 4; y++)
#pragma unroll
    for (int x = 0; x < 4; x++) {
      const int col = j0 + tx * 4 + x;
      C[(size_t)(i0 + ty * 4 + y) * D_SEM + col] = acc[y][x] + bias[col];
    }
}

// ---------------------------------------------------------------------------
// Per-chunk block-diagonal Gram: G[z][i][j] = c_i . c_j within block z.
// grid (4,4,CHUNK_BLKS), 64x64 tiles, K=1024.
// ---------------------------------------------------------------------------
__global__ __launch_bounds__(256)
void gram_kernel(const float* __restrict__ Cc, float* __restrict__ G) {
  const int z = blockIdx.z;
  const float* A = Cc + (size_t)z * B_ITEMS * D_SEM;
  __shared__ float As[16][68];
  __shared__ float Bs[16][68];
  const int t = threadIdx.x;
  const int ty = t >> 4, tx = t & 15;
  const int i0 = blockIdx.x * 64, j0 = blockIdx.y * 64;
  const int lrow = t >> 2, lcol = (t & 3) << 2;
  float acc[4][4] = {{0.f}};
  const float* ap = A + (size_t)(i0 + lrow) * D_SEM + lcol;
  const float* wp = A + (size_t)(j0 + lrow) * D_SEM + lcol;
  for (int k0 = 0; k0 < D_SEM; k0 += 16) {
    float4 av = *(const float4*)(ap + k0);
    float4 wv = *(const float4*)(wp + k0);
    __syncthreads();
    As[lcol + 0][lrow] = av.x; As[lcol + 1][lrow] = av.y;
    As[lcol + 2][lrow] = av.z; As[lcol + 3][lrow] = av.w;
    Bs[lcol + 0][lrow] = wv.x; Bs[lcol + 1][lrow] = wv.y;
    Bs[lcol + 2][lrow] = wv.z; Bs[lcol + 3][lrow] = wv.w;
    __syncthreads();
#pragma unroll
    for (int kk = 0; kk < 16; kk++) {
      float a[4], b[4];
#pragma unroll
      for (int y = 0; y < 4; y++) a[y] = As[kk][ty * 4 + y];
#pragma unroll
      for (int x = 0; x < 4; x++) b[x] = Bs[kk][tx * 4 + x];
#pragma unroll
      for (int y = 0; y < 4; y++)
#pragma unroll
        for (int x = 0; x < 4; x++) acc[y][x] = fmaf(a[y], b[x], acc[y][x]);
    }
  }
  float* Gz = G + (size_t)z * B_ITEMS * B_ITEMS;
#pragma unroll
  for (int y = 0; y < 4; y++)
#pragma unroll
    for (int x = 0; x < 4; x++)
      Gz[(size_t)(i0 + ty * 4 + y) * B_ITEMS + j0 + tx * 4 + x] = acc[y][x];
}

// ---------------------------------------------------------------------------
// Per-block dot-product matrix: P0[i][s] = c_i . t_s(block start).  Read-only
// in the scan.  Tiles past the max-possible-valid limit are zero-filled
// (finite; invalid slots are masked by n_reg=+inf in the scan).  grid (4,64).
// ---------------------------------------------------------------------------
__global__ __launch_bounds__(256)
void pgemm_kernel(const float* __restrict__ A,   // content block 256 x 1024
                  const float* __restrict__ T,   // traces (= out) 4096 x 1024
                  float* __restrict__ P,
                  const int* __restrict__ state) {
  const int limit = min(state[0] + B_ITEMS, S_SLOTS);
  const int j0 = blockIdx.y * 64;
  const int i0 = blockIdx.x * 64;
  const int t = threadIdx.x;
  const int ty = t >> 4, tx = t & 15;
  if (j0 >= limit) {
    const float4 z = {0.f, 0.f, 0.f, 0.f};
    const int col = j0 + tx * 4;
#pragma unroll
    for (int y = 0; y < 4; y++)
      *(float4*)(P + (size_t)(i0 + ty * 4 + y) * S_SLOTS + col) = z;
    return;
  }
  __shared__ float As[16][68];
  __shared__ float Bs[16][68];
  const int lrow = t >> 2, lcol = (t & 3) << 2;
  float acc[4][4] = {{0.f}};
  const float* ap = A + (size_t)(i0 + lrow) * D_SEM + lcol;
  const float* wp = T + (size_t)(j0 + lrow) * D_SEM + lcol;
  for (int k0 = 0; k0 < D_SEM; k0 += 16) {
    float4 av = *(const float4*)(ap + k0);
    float4 wv = *(const float4*)(wp + k0);
    __syncthreads();
    As[lcol + 0][lrow] = av.x; As[lcol + 1][lrow] = av.y;
    As[lcol + 2][lrow] = av.z; As[lcol + 3][lrow] = av.w;
    Bs[lcol + 0][lrow] = wv.x; Bs[lcol + 1][lrow] = wv.y;
    Bs[lcol + 2][lrow] = wv.z; Bs[lcol + 3][lrow] = wv.w;
    __syncthreads();
#pragma unroll
    for (int kk = 0; kk < 16; kk++) {
      float a[4], b[4];
#pragma unroll
      for (int y = 0; y < 4; y++) a[y] = As[kk][ty * 4 + y];
#pragma unroll
      for (int x = 0; x < 4; x++) b[x] = Bs[kk][tx * 4 + x];
#pragma unroll
      for (int y = 0; y < 4; y++)
#pragma unroll
        for (int x = 0; x < 4; x++) acc[y][x] = fmaf(a[y], b[x], acc[y][x]);
    }
  }
#pragma unroll
  for (int y = 0; y < 4; y++)
#pragma unroll
    for (int x = 0; x < 4; x++)
      P[(size_t)(i0 + ty * 4 + y) * S_SLOTS + j0 + tx * 4 + x] = acc[y][x];
}

// ---------------------------------------------------------------------------
// init: copy traces0 -> out (working traces), n_g[s] = ||t_s||^2, reset state.
// ---------------------------------------------------------------------------
__global__ __launch_bounds__(256)
void init_kernel(const float* __restrict__ traces0, float* __restrict__ out,
                 float* __restrict__ n_g, int* __restrict__ state) {
  __shared__ float wsum[4];
  const int s = blockIdx.x, t = threadIdx.x;
  const int lane = t & 63, wave = t >> 6;
  float4 v = *(const float4*)(traces0 + (size_t)s * D_SEM + 4 * t);
  *(float4*)(out + (size_t)s * D_SEM + 4 * t) = v;
  float nn = v.x * v.x + v.y * v.y + v.z * v.z + v.w * v.w;
#pragma unroll
  for (int o = 32; o; o >>= 1) nn += __shfl_down(nn, o, 64);
  if (lane == 0) wsum[wave] = nn;
  __syncthreads();
  if (t == 0) n_g[s] = wsum[0] + wsum[1] + wsum[2] + wsum[3];
  if (s == 0 && t == 0) { state[0] = 0; state[1] = 0; }
}

// ---------------------------------------------------------------------------
// DPP wave64 min (f32): row_shr 1/2/4/8 then row_bcast15 (rows 1,3) and
// row_bcast31 (rows 2,3); lane 63 holds the wave min; readlane broadcasts.
// ---------------------------------------------------------------------------
__device__ __forceinline__ float wave_min_f32(float x) {
  int xi = __float_as_int(x), y;
  y = __builtin_amdgcn_update_dpp(xi, xi, 0x111, 0xF, 0xF, false);  // row_shr:1
  x = fminf(x, __int_as_float(y)); xi = __float_as_int(x);
  y = __builtin_amdgcn_update_dpp(xi, xi, 0x112, 0xF, 0xF, false);  // row_shr:2
  x = fminf(x, __int_as_float(y)); xi = __float_as_int(x);
  y = __builtin_amdgcn_update_dpp(xi, xi, 0x114, 0xF, 0xF, false);  // row_shr:4
  x = fminf(x, __int_as_float(y)); xi = __float_as_int(x);
  y = __builtin_amdgcn_update_dpp(xi, xi, 0x118, 0xF, 0xF, false);  // row_shr:8
  x = fminf(x, __int_as_float(y)); xi = __float_as_int(x);
  y = __builtin_amdgcn_update_dpp(xi, xi, 0x142, 0xA, 0xF, false);  // row_bcast:15
  x = fminf(x, __int_as_float(y)); xi = __float_as_int(x);
  y = __builtin_amdgcn_update_dpp(xi, xi, 0x143, 0xC, 0xF, false);  // row_bcast:31
  x = fminf(x, __int_as_float(y)); xi = __float_as_int(x);
  return __int_as_float(__builtin_amdgcn_readlane(xi, 63));
}

// ---------------------------------------------------------------------------
// Sequential scan, one WG, 256 thr.  Thread t owns slots [16t,16t+16).
// NO scalar (s_load) traffic in the loop: G rows are staged through an LDS
// ring grow[8][256] (per-thread vector load of row I+4, delayed 2 steps
// before its ds_write of row I+2), rewards preloaded to LDS.  All uniform
// scalars (gi, g1, reward, scatter G value) are LDS broadcast reads issued
// PRE-barrier, so the forced lgkmcnt(0) only drains fast LDS ops.
// Decision machinery identical to R5 (f32 DPP argmin, corr-parity scatter,
// single barrier, no global stores in loop).
// ---------------------------------------------------------------------------
#define CORR_SZ 4352   // 4096 + 4096/16 (stride-17 swizzle)
#define SWZ(s) ((s) + ((s) >> 4))

__global__ __launch_bounds__(256, 1)
void scan_kernel(const float* __restrict__ P, const float* __restrict__ Gb,
                 const float* __restrict__ rewards, const float* __restrict__ n_g,
                 int* __restrict__ state, u64* __restrict__ decs) {
  __shared__ float corr0[CORR_SZ];
  __shared__ float corr1[CORR_SZ];
  __shared__ float grow[8][B_ITEMS];   // G-row ring (8 KB)
  __shared__ float rew_l[B_ITEMS];
  __shared__ u64 partials[2][4];
  const int t = threadIdx.x;          // 0..255
  const int lane = t & 63, wave = t >> 6;
  const int s_base = t << 4;
  const int c_base = 17 * t;          // SWZ(s_base + k) == c_base + k

  int num = state[0];
  int ptr = state[1];

  for (int s = t; s < CORR_SZ; s += 256) { corr0[s] = 0.f; corr1[s] = 0.f; }
  rew_l[t] = rewards[t];
  grow[0][t] = Gb[t];                       // G row 0
  grow[1][t] = Gb[B_ITEMS + t];             // G row 1
  float pend_a = Gb[2 * B_ITEMS + t];       // G row 2 (written at step 0)
  float pend_b = Gb[3 * B_ITEMS + t];       // G row 3 (written at step 1)

  // per-slot ||t_s||^2 in owner registers; +inf marks invalid
  float n_reg[16];
#pragma unroll
  for (int k = 0; k < 16; k += 4) {
    float4 nv = *(const float4*)(n_g + s_base + k);
    n_reg[k + 0] = (s_base + k + 0 < num) ? nv.x : __uint_as_float(0x7F800000u);
    n_reg[k + 1] = (s_base + k + 1 < num) ? nv.y : __uint_as_float(0x7F800000u);
    n_reg[k + 2] = (s_base + k + 2 < num) ? nv.z : __uint_as_float(0x7F800000u);
    n_reg[k + 3] = (s_base + k + 3 < num) ? nv.w : __uint_as_float(0x7F800000u);
  }
  float alpha_r[16];
#pragma unroll
  for (int k = 0; k < 16; k++) alpha_r[k] = 1.f;

  // p_cur = row 0 (fully corrected at loop entry)
  float p_cur[16];
#pragma unroll
  for (int k = 0; k < 16; k += 4) {
    float4 v0 = *(const float4*)(P + s_base + k);
    p_cur[k] = v0.x; p_cur[k + 1] = v0.y; p_cur[k + 2] = v0.z; p_cur[k + 3] = v0.w;
  }

  // raw ping-pong: buffer A holds P row 1 initially
  float raw_a[16], raw_b[16];
  {
    const float* rp = P + (size_t)S_SLOTS + s_base;
#pragma unroll
    for (int k = 0; k < 16; k += 4) {
      float4 v = *(const float4*)(rp + k);
      raw_a[k] = v.x; raw_a[k + 1] = v.y; raw_a[k + 2] = v.z; raw_a[k + 3] = v.w;
    }
#pragma unroll
    for (int k = 0; k < 16; k++) raw_b[k] = 0.f;
  }

  int my_cslot = -1; float my_coeff = 0.f;   // thread t's decision entry
  u32 my_slot = 0; float my_lr = 0.f;        // decision latch for decs[]

  __syncthreads();   // prologue LDS (corr zero, grow rows 0/1, rew) visible

#define OWNFIX(K, I) { const float nold = n_reg[K]; \
    if (upd) { \
      n_reg[K] = omr * omr * nold + 2.0f * lr * omr * p_cur[K] + lr * lr * gi_l; \
      alpha_r[K] = __fmul_rn(alpha_r[K], omr); \
      if ((I) + 1 < B_ITEMS) cv[K] = fmaf(omr, cv[K], __fmul_rn(lr, g1)); \
    } else { n_reg[K] = gi_l; alpha_r[K] = 0.f; \
      if ((I) + 1 < B_ITEMS) cv[K] = g1; } }

#define SCAN_STEP(I, CBUF, RAWC, RAWN, PEND) { \
    /* G-row staging: write row I+2 (loaded 2 steps ago), load row I+4 */ \
    if ((I) + 2 < B_ITEMS) grow[((I) + 2) & 7][t] = PEND; \
    if ((I) + 4 < B_ITEMS) PEND = Gb[(size_t)((I) + 4) * B_ITEMS + t]; \
    /* prefetch raw P row I+2 */ \
    if ((I) + 2 < B_ITEMS) { \
      const float* rp = P + (size_t)((I) + 2) * S_SLOTS + s_base; \
      _Pragma("unroll") \
      for (int k = 0; k < 16; k += 4) { \
        float4 v = *(const float4*)(rp + k); \
        RAWN[k] = v.x; RAWN[k + 1] = v.y; RAWN[k + 2] = v.z; RAWN[k + 3] = v.w; \
      } \
    } \
    /* uniform LDS broadcast reads (early; consumed post-barrier) */ \
    const float gi_l = grow[(I) & 7][(I)]; \
    const float riv = rew_l[(I)]; \
    float g1 = 0.f; \
    if ((I) + 1 < B_ITEMS) g1 = grow[(I) & 7][(I) + 1]; \
    /* SCATTER for entering row I+1 (coeffs S_{I-1}); G[I+1][t] via LDS */ \
    if ((I) + 1 < B_ITEMS && my_coeff != 0.f) \
      atomicAdd(&CBUF[SWZ(my_cslot)], \
                __fmul_rn(my_coeff, grow[((I) + 1) & 7][t])); \
    /* KEYS: f32 d2 per owned slot; local min + lowest-index resolve */ \
    float d2[16]; \
    _Pragma("unroll") \
    for (int k = 0; k < 16; k++) { \
      const float v = fmaf(-2.0f, p_cur[k], n_reg[k] + gi_l); \
      d2[k] = (v > 0.f) ? v : 0.f; \
    } \
    float dloc = d2[0]; \
    _Pragma("unroll") \
    for (int k = 1; k < 16; k++) dloc = fminf(dloc, d2[k]); \
    u32 iloc = 0; \
    _Pragma("unroll") \
    for (int k = 15; k >= 1; k--) if (d2[k] == dloc) iloc = (u32)k; \
    const u32 sloc = (u32)s_base + iloc; \
    /* wave min via DPP + ballot (lowest lane, exact tie-break) */ \
    const float dmin = wave_min_f32(dloc); \
    const u64 bmask = __ballot(dloc == dmin); \
    const int bl = __ffsll((unsigned long long)bmask) - 1; \
    const u32 swave = (u32)__builtin_amdgcn_readlane((int)sloc, bl); \
    if (lane == 0) \
      partials[(I) & 1][wave] = ((u64)__float_as_uint(dmin) << 32) | swave; \
    asm volatile("s_waitcnt lgkmcnt(0)" ::: "memory"); \
    __builtin_amdgcn_s_barrier(); \
    __builtin_amdgcn_sched_barrier(0); \
    /* DEC: redundant decision; read own corr slice */ \
    u64 bk = partials[(I) & 1][0]; \
    { u64 v = partials[(I) & 1][1]; if (v < bk) bk = v; \
      v = partials[(I) & 1][2]; if (v < bk) bk = v; \
      v = partials[(I) & 1][3]; if (v < bk) bk = v; } \
    float cv[16]; \
    if ((I) + 1 < B_ITEMS) { \
      _Pragma("unroll") \
      for (int k = 0; k < 16; k++) cv[k] = CBUF[c_base + k]; \
    } else { \
      _Pragma("unroll") \
      for (int k = 0; k < 16; k++) cv[k] = 0.f; \
    } \
    const float d2b = __uint_as_float((u32)(bk >> 32)); \
    const int nslot = (int)(u32)bk; \
    const bool upd = (num > 0) && (d2b < 4.0f); \
    const float lr = __fmul_rn(0.01f, __fadd_rn(1.0f, fabsf(riv))); \
    const int slot = upd ? nslot : ptr; \
    const float omr = 1.0f - lr; \
    if (!upd) { num = min(num + 1, S_SLOTS); ptr = (ptr + 1) & (S_SLOTS - 1); } \
    if ((I) == t) { my_slot = (u32)slot | (upd ? 0x80000000u : 0u); my_lr = lr; } \
    if (my_cslot == slot) my_coeff = upd ? __fmul_rn(my_coeff, omr) : 0.f; \
    if ((I) == t) { my_cslot = slot; my_coeff = upd ? lr : 1.f; } \
    /* owner: n/alpha recurrence + cv fix for decision I */ \
    if ((slot >> 4) == t) { \
      switch (slot & 15) { \
        case 0:  OWNFIX(0,  I) break; case 1:  OWNFIX(1,  I) break; \
        case 2:  OWNFIX(2,  I) break; case 3:  OWNFIX(3,  I) break; \
        case 4:  OWNFIX(4,  I) break; case 5:  OWNFIX(5,  I) break; \
        case 6:  OWNFIX(6,  I) break; case 7:  OWNFIX(7,  I) break; \
        case 8:  OWNFIX(8,  I) break; case 9:  OWNFIX(9,  I) break; \
        case 10: OWNFIX(10, I) break; case 11: OWNFIX(11, I) break; \
        case 12: OWNFIX(12, I) break; case 13: OWNFIX(13, I) break; \
        case 14: OWNFIX(14, I) break; default: OWNFIX(15, I) break; \
      } \
    } \
    /* ENTER row I+1: p_cur = alpha*raw + cv; zero own corr entries */ \
    if ((I) + 1 < B_ITEMS) { \
      _Pragma("unroll") \
      for (int k = 0; k < 16; k++) { \
        p_cur[k] = fmaf(alpha_r[k], RAWC[k], cv[k]); \
        CBUF[c_base + k] = 0.f; \
      } \
    } \
  }

  for (int i = 0; i < B_ITEMS; i += 2) {
    SCAN_STEP(i,     corr0, raw_a, raw_b, pend_a)
    SCAN_STEP(i + 1, corr1, raw_b, raw_a, pend_b)
  }
#undef SCAN_STEP
#undef OWNFIX

  if (t == 0) { state[0] = num; state[1] = ptr; }
  decs[t] = ((u64)__float_as_uint(my_lr) << 32) | (u64)my_slot;
}

// ---------------------------------------------------------------------------
// apply: materialize the block's trace mutations. WG j owns slot_j iff step j
// is the LAST step touching it. Composition: t = alpha*t_snap + sum beta_j c_j.
// Recomputes exact ||t||^2 -> n_g (bounds numeric drift to one block).
// ---------------------------------------------------------------------------
__global__ __launch_bounds__(256)
void apply_kernel(const float* __restrict__ content,  // block 256 x 1024
                  const u64* __restrict__ decs,       // 256 decisions
                  float* __restrict__ traces,         // = out
                  float* __restrict__ n_g) {
  __shared__ u32 aslot[B_ITEMS];
  __shared__ float alr[B_ITEMS];
  __shared__ float betas[B_ITEMS];
  __shared__ int notowner;
  __shared__ float wsum[4];
  const int t = threadIdx.x, j = blockIdx.x;
  const int lane = t & 63, wave = t >> 6;
  const u64 d = decs[t];
  aslot[t] = (u32)(d & 0xFFFFFFFFull);
  alr[t] = __uint_as_float((u32)(d >> 32));
  if (t == 0) notowner = 0;
  __syncthreads();
  const u32 myslot = aslot[j] & 0x7FFFFFFFu;
  if (t > j && (aslot[t] & 0x7FFFFFFFu) == myslot) notowner = 1;
  __syncthreads();
  if (notowner) return;

  float alpha = 1.f, beta = 0.f;
  for (int k = 0; k < B_ITEMS; k++) {
    const u32 a = aslot[k];
    if ((a & 0x7FFFFFFFu) == myslot) {
      const float lr = alr[k];
      if (a & 0x80000000u) {           // update
        const float om = 1.f - lr;
        alpha *= om; beta *= om;
        if (t == k) beta += lr;
      } else {                         // insert
        alpha = 0.f; beta = (t == k) ? 1.f : 0.f;
      }
    }
  }
  betas[t] = beta;
  __syncthreads();

  float4 v = *(const float4*)(traces + (size_t)myslot * D_SEM + 4 * t);
  v.x *= alpha; v.y *= alpha; v.z *= alpha; v.w *= alpha;
  for (int k = 0; k < B_ITEMS; k++) {
    if ((aslot[k] & 0x7FFFFFFFu) == myslot) {
      const float bk = betas[k];
      const float4 c = *(const float4*)(content + (size_t)k * D_SEM + 4 * t);
      v.x = fmaf(bk, c.x, v.x); v.y = fmaf(bk, c.y, v.y);
      v.z = fmaf(bk, c.z, v.z); v.w = fmaf(bk, c.w, v.w);
    }
  }
  *(float4*)(traces + (size_t)myslot * D_SEM + 4 * t) = v;
  float nn = v.x * v.x + v.y * v.y + v.z * v.z + v.w * v.w;
#pragma unroll
  for (int o = 32; o; o >>= 1) nn += __shfl_down(nn, o, 64);
  if (lane == 0) wsum[wave] = nn;
  __syncthreads();
  if (t == 0) n_g[myslot] = wsum[0] + wsum[1] + wsum[2] + wsum[3];
}

// ---------------------------------------------------------------------------
// finalize: parallel strengths replay via two-pass LDS histogram.
// Per slot: final strength = 1 + (#updates after last insert) if ever
// inserted, else strengths0 + #updates.  Then masked mean + scalars.
// ---------------------------------------------------------------------------
__global__ __launch_bounds__(256)
void finalize_kernel(const float* __restrict__ strengths0,
                     const u64* __restrict__ decs,
                     const int* __restrict__ state, float* __restrict__ out) {
  __shared__ int last_ins[S_SLOTS];
  __shared__ int cnt[S_SLOTS];
  __shared__ float wsum[4];
  const int t = threadIdx.x, lane = t & 63, wave = t >> 6;
  for (int s = t; s < S_SLOTS; s += 256) { last_ins[s] = -1; cnt[s] = 0; }
  __syncthreads();
  // pass 1: last insert index per slot
  for (int k = t; k < N_ITEMS; k += 256) {
    const u32 dd = (u32)(decs[k] & 0xFFFFFFFFull);
    if (!(dd & 0x80000000u)) atomicMax(&last_ins[(int)dd], k);
  }
  __syncthreads();
  // pass 2: count updates after the last insert
  for (int k = t; k < N_ITEMS; k += 256) {
    const u32 dd = (u32)(decs[k] & 0xFFFFFFFFull);
    const int slot = (int)(dd & 0x7FFFFFFFu);
    if ((dd & 0x80000000u) && k > last_ins[slot]) atomicAdd(&cnt[slot], 1);
  }
  __syncthreads();
  const int num = state[0];
  float* outs = out + (size_t)S_SLOTS * D_SEM;
  float lsum = 0.f;
  for (int s = t; s < S_SLOTS; s += 256) {
    const float base = (last_ins[s] >= 0) ? 1.f : strengths0[s];
    const float v = base + (float)cnt[s];
    outs[s] = v;
    if (s < num) lsum += v;
  }
#pragma unroll
  for (int o = 32; o; o >>= 1) lsum += __shfl_down(lsum, o, 64);
  if (lane == 0) wsum[wave] = lsum;
  __syncthreads();
  if (t == 0) {
    const float total = wsum[0] + wsum[1] + wsum[2] + wsum[3];
    float denom = (float)num;
    if (denom < 1.f) denom = 1.f;
    outs[S_SLOTS + 0] = (float)num;
    outs[S_SLOTS + 1] = (float)N_ITEMS;
    outs[S_SLOTS + 2] = (num > 0) ? (total / denom) : 0.f;
  }
}

// ---------------------------------------------------------------------------
extern "C" void kernel_launch(void* const* d_in, const int* in_sizes, int n_in,
                              void* d_out, int out_size, void* d_ws, size_t ws_size,
                              hipStream_t stream) {
  const float* states  = (const float*)d_in[0];
  const float* rewards = (const float*)d_in[1];
  const float* W       = (const float*)d_in[2];
  const float* bias    = (const float*)d_in[3];
  const float* traces0 = (const float*)d_in[4];
  const float* str0    = (const float*)d_in[5];
  float* out = (float*)d_out;   // traces live here (working + final)

  // ws layout (~24.5 MB): content chunk 16MB | P 4MB | Gram 4MB | n_g | decs | state
  char* p = (char*)d_ws;
  float* cbuf = (float*)p;                 p += (size_t)CHUNK_ITEMS * D_SEM * 4;
  float* P    = (float*)p;                 p += (size_t)B_ITEMS * S_SLOTS * 4;
  float* Gb   = (float*)p;                 p += (size_t)CHUNK_BLKS * B_ITEMS * B_ITEMS * 4;
  float* n_g  = (float*)p;                 p += (size_t)S_SLOTS * 4;
  u64*   decs = (u64*)p;                   p += (size_t)N_ITEMS * 8;
  int*   state = (int*)p;

  init_kernel<<<S_SLOTS, 256, 0, stream>>>(traces0, out, n_g, state);

  for (int c = 0; c < N_ITEMS / CHUNK_ITEMS; c++) {
    gemm_kernel<<<dim3(CHUNK_ITEMS / 64, D_SEM / 64), 256, 0, stream>>>(
        states + (size_t)c * CHUNK_ITEMS * D_STATE, W, bias, cbuf);
    gram_kernel<<<dim3(4, 4, CHUNK_BLKS), 256, 0, stream>>>(cbuf, Gb);
    for (int bb = 0; bb < CHUNK_BLKS; bb++) {
      const int b = c * CHUNK_BLKS + bb;
      const float* cblk = cbuf + (size_t)bb * B_ITEMS * D_SEM;
      const float* Gblk = Gb + (size_t)bb * B_ITEMS * B_ITEMS;
      pgemm_kernel<<<dim3(4, S_SLOTS / 64), 256, 0, stream>>>(cblk, out, P, state);
      scan_kernel<<<1, 256, 0, stream>>>(P, Gblk, rewards + (size_t)b * B_ITEMS,
                                         n_g, state, decs + (size_t)b * B_ITEMS);
      apply_kernel<<<B_ITEMS, 256, 0, stream>>>(cblk, decs + (size_t)b * B_ITEMS,
                                                out, n_g);
    }
  }
  finalize_kernel<<<1, 256, 0, stream>>>(str0, decs, state, out);
}

// Round 8
// 29498.126 us; speedup vs baseline: 1.1315x; 1.0862x over previous
//
#include <hip/hip_runtime.h>
#include <cstdint>
#include <cstddef>

// Problem constants (match reference)
#define N_ITEMS 16384
#define D_STATE 2048
#define D_SEM   1024
#define S_SLOTS 4096
#define DTHRESH 2.0f

#define B_ITEMS 256              // sequential-scan block size
#define NBLK    (N_ITEMS / B_ITEMS)   // 64
#define CHUNK_BLKS 16            // content-GEMM chunking (16 MB buffer)
#define CHUNK_ITEMS (B_ITEMS * CHUNK_BLKS)  // 4096

typedef unsigned long long u64;
typedef unsigned int u32;

// ---------------------------------------------------------------------------
// Content GEMM: C[i,j] = sum_d A[i,d]*W[j,d] + b[j].  64x64 tile, K=2048.
// ---------------------------------------------------------------------------
__global__ __launch_bounds__(256)
void gemm_kernel(const float* __restrict__ A, const float* __restrict__ W,
                 const float* __restrict__ bias, float* __restrict__ C) {
  __shared__ float As[16][68];
  __shared__ float Bs[16][68];
  const int t = threadIdx.x;
  const int ty = t >> 4, tx = t & 15;
  const int i0 = blockIdx.x * 64, j0 = blockIdx.y * 64;
  const int lrow = t >> 2, lcol = (t & 3) << 2;
  float acc[4][4] = {{0.f}};
  const float* ap = A + (size_t)(i0 + lrow) * D_STATE + lcol;
  const float* wp = W + (size_t)(j0 + lrow) * D_STATE + lcol;
  for (int k0 = 0; k0 < D_STATE; k0 += 16) {
    float4 av = *(const float4*)(ap + k0);
    float4 wv = *(const float4*)(wp + k0);
    __syncthreads();
    As[lcol + 0][lrow] = av.x; As[lcol + 1][lrow] = av.y;
    As[lcol + 2][lrow] = av.z; As[lcol + 3][lrow] = av.w;
    Bs[lcol + 0][lrow] = wv.x; Bs[lcol + 1][lrow] = wv.y;
    Bs[lcol + 2][lrow] = wv.z; Bs[lcol + 3][lrow] = wv.w;
    __syncthreads();
#pragma unroll
    for (int kk = 0; kk < 16; kk++) {
      float a[4], b[4];
#pragma unroll
      for (int y = 0; y < 4; y++) a[y] = As[kk][ty * 4 + y];
#pragma unroll
      for (int x = 0; x < 4; x++) b[x] = Bs[kk][tx * 4 + x];
#pragma unroll
      for (int y = 0; y < 4; y++)
#pragma unroll
        for (int x = 0; x < 4; x++) acc[y][x] = fmaf(a[y], b[x], acc[y][x]);
    }
  }
#pragma unroll
  for (int y = 0; y < 4; y++)
#pragma unroll
    for (int x = 0; x < 4; x++) {
      const int col = j0 + tx * 4 + x;
      C[(size_t)(i0 + ty * 4 + y) * D_SEM + col] = acc[y][x] + bias[col];
    }
}

// ---------------------------------------------------------------------------
// Per-chunk block-diagonal Gram: G[z][i][j] = c_i . c_j within block z.
// grid (4,4,CHUNK_BLKS), 64x64 tiles, K=1024.
// ---------------------------------------------------------------------------
__global__ __launch_bounds__(256)
void gram_kernel(const float* __restrict__ Cc, float* __restrict__ G) {
  const int z = blockIdx.z;
  const float* A = Cc + (size_t)z * B_ITEMS * D_SEM;
  __shared__ float As[16][68];
  __shared__ float Bs[16][68];
  const int t = threadIdx.x;
  const int ty = t >> 4, tx = t & 15;
  const int i0 = blockIdx.x * 64, j0 = blockIdx.y * 64;
  const int lrow = t >> 2, lcol = (t & 3) << 2;
  float acc[4][4] = {{0.f}};
  const float* ap = A + (size_t)(i0 + lrow) * D_SEM + lcol;
  const float* wp = A + (size_t)(j0 + lrow) * D_SEM + lcol;
  for (int k0 = 0; k0 < D_SEM; k0 += 16) {
    float4 av = *(const float4*)(ap + k0);
    float4 wv = *(const float4*)(wp + k0);
    __syncthreads();
    As[lcol + 0][lrow] = av.x; As[lcol + 1][lrow] = av.y;
    As[lcol + 2][lrow] = av.z; As[lcol + 3][lrow] = av.w;
    Bs[lcol + 0][lrow] = wv.x; Bs[lcol + 1][lrow] = wv.y;
    Bs[lcol + 2][lrow] = wv.z; Bs[lcol + 3][lrow] = wv.w;
    __syncthreads();
#pragma unroll
    for (int kk = 0; kk < 16; kk++) {
      float a[4], b[4];
#pragma unroll
      for (int y = 0; y < 4; y++) a[y] = As[kk][ty * 4 + y];
#pragma unroll
      for (int x = 0; x < 4; x++) b[x] = Bs[kk][tx * 4 + x];
#pragma unroll
      for (int y = 0; y < 4; y++)
#pragma unroll
        for (int x = 0; x < 4; x++) acc[y][x] = fmaf(a[y], b[x], acc[y][x]);
    }
  }
  float* Gz = G + (size_t)z * B_ITEMS * B_ITEMS;
#pragma unroll
  for (int y = 0; y < 4; y++)
#pragma unroll
    for (int x = 0; x < 4; x++)
      Gz[(size_t)(i0 + ty * 4 + y) * B_ITEMS + j0 + tx * 4 + x] = acc[y][x];
}

// ---------------------------------------------------------------------------
// Per-block dot-product matrix: P0[i][s] = c_i . t_s(block start).  Read-only
// in the scan.  Tiles past the max-possible-valid limit are zero-filled
// (finite; invalid slots are masked by n_reg=+inf in the scan).  grid (4,64).
// ---------------------------------------------------------------------------
__global__ __launch_bounds__(256)
void pgemm_kernel(const float* __restrict__ A,   // content block 256 x 1024
                  const float* __restrict__ T,   // traces (= out) 4096 x 1024
                  float* __restrict__ P,
                  const int* __restrict__ state) {
  const int limit = min(state[0] + B_ITEMS, S_SLOTS);
  const int j0 = blockIdx.y * 64;
  const int i0 = blockIdx.x * 64;
  const int t = threadIdx.x;
  const int ty = t >> 4, tx = t & 15;
  if (j0 >= limit) {
    const float4 z = {0.f, 0.f, 0.f, 0.f};
    const int col = j0 + tx * 4;
#pragma unroll
    for (int y = 0; y < 4; y++)
      *(float4*)(P + (size_t)(i0 + ty * 4 + y) * S_SLOTS + col) = z;
    return;
  }
  __shared__ float As[16][68];
  __shared__ float Bs[16][68];
  const int lrow = t >> 2, lcol = (t & 3) << 2;
  float acc[4][4] = {{0.f}};
  const float* ap = A + (size_t)(i0 + lrow) * D_SEM + lcol;
  const float* wp = T + (size_t)(j0 + lrow) * D_SEM + lcol;
  for (int k0 = 0; k0 < D_SEM; k0 += 16) {
    float4 av = *(const float4*)(ap + k0);
    float4 wv = *(const float4*)(wp + k0);
    __syncthreads();
    As[lcol + 0][lrow] = av.x; As[lcol + 1][lrow] = av.y;
    As[lcol + 2][lrow] = av.z; As[lcol + 3][lrow] = av.w;
    Bs[lcol + 0][lrow] = wv.x; Bs[lcol + 1][lrow] = wv.y;
    Bs[lcol + 2][lrow] = wv.z; Bs[lcol + 3][lrow] = wv.w;
    __syncthreads();
#pragma unroll
    for (int kk = 0; kk < 16; kk++) {
      float a[4], b[4];
#pragma unroll
      for (int y = 0; y < 4; y++) a[y] = As[kk][ty * 4 + y];
#pragma unroll
      for (int x = 0; x < 4; x++) b[x] = Bs[kk][tx * 4 + x];
#pragma unroll
      for (int y = 0; y < 4; y++)
#pragma unroll
        for (int x = 0; x < 4; x++) acc[y][x] = fmaf(a[y], b[x], acc[y][x]);
    }
  }
#pragma unroll
  for (int y = 0; y < 4; y++)
#pragma unroll
    for (int x = 0; x < 4; x++)
      P[(size_t)(i0 + ty * 4 + y) * S_SLOTS + j0 + tx * 4 + x] = acc[y][x];
}

// ---------------------------------------------------------------------------
// init: copy traces0 -> out (working traces), n_g[s] = ||t_s||^2, reset state.
// ---------------------------------------------------------------------------
__global__ __launch_bounds__(256)
void init_kernel(const float* __restrict__ traces0, float* __restrict__ out,
                 float* __restrict__ n_g, int* __restrict__ state) {
  __shared__ float wsum[4];
  const int s = blockIdx.x, t = threadIdx.x;
  const int lane = t & 63, wave = t >> 6;
  float4 v = *(const float4*)(traces0 + (size_t)s * D_SEM + 4 * t);
  *(float4*)(out + (size_t)s * D_SEM + 4 * t) = v;
  float nn = v.x * v.x + v.y * v.y + v.z * v.z + v.w * v.w;
#pragma unroll
  for (int o = 32; o; o >>= 1) nn += __shfl_down(nn, o, 64);
  if (lane == 0) wsum[wave] = nn;
  __syncthreads();
  if (t == 0) n_g[s] = wsum[0] + wsum[1] + wsum[2] + wsum[3];
  if (s == 0 && t == 0) { state[0] = 0; state[1] = 0; }
}

// ---------------------------------------------------------------------------
// DPP wave64 min (f32): row_shr 1/2/4/8 then row_bcast15 (rows 1,3) and
// row_bcast31 (rows 2,3); lane 63 holds the wave min; readlane broadcasts.
// ---------------------------------------------------------------------------
__device__ __forceinline__ float wave_min_f32(float x) {
  int xi = __float_as_int(x), y;
  y = __builtin_amdgcn_update_dpp(xi, xi, 0x111, 0xF, 0xF, false);  // row_shr:1
  x = fminf(x, __int_as_float(y)); xi = __float_as_int(x);
  y = __builtin_amdgcn_update_dpp(xi, xi, 0x112, 0xF, 0xF, false);  // row_shr:2
  x = fminf(x, __int_as_float(y)); xi = __float_as_int(x);
  y = __builtin_amdgcn_update_dpp(xi, xi, 0x114, 0xF, 0xF, false);  // row_shr:4
  x = fminf(x, __int_as_float(y)); xi = __float_as_int(x);
  y = __builtin_amdgcn_update_dpp(xi, xi, 0x118, 0xF, 0xF, false);  // row_shr:8
  x = fminf(x, __int_as_float(y)); xi = __float_as_int(x);
  y = __builtin_amdgcn_update_dpp(xi, xi, 0x142, 0xA, 0xF, false);  // row_bcast:15
  x = fminf(x, __int_as_float(y)); xi = __float_as_int(x);
  y = __builtin_amdgcn_update_dpp(xi, xi, 0x143, 0xC, 0xF, false);  // row_bcast:31
  x = fminf(x, __int_as_float(y)); xi = __float_as_int(x);
  return __int_as_float(__builtin_amdgcn_readlane(xi, 63));
}

// ---------------------------------------------------------------------------
// Sequential scan, ONE WG of 512 threads (8 waves = 2/SIMD for TLP).
// Thread t owns slots [8t, 8t+8).  Same algorithm as R6: P0 read-only,
// trace state t_s = alpha_s*t_s0 + sum coeff_j*c_j (entry j owned by thread
// j<256), LDS G-row ring + preloaded rewards (no scalar loads in loop),
// f32 DPP argmin, corr-parity scatter, ONE lgkm-only barrier per step.
// Halving slots/thread shortens each wave's dependent chain ~40% and the
// 2-waves/SIMD interleave hides dep-stall latency (the R6 bottleneck).
// ---------------------------------------------------------------------------
#define CORR_SZ 4352   // 4096 + 4096/16 (stride-17-per-16 swizzle)
#define SWZ(s) ((s) + ((s) >> 4))

__global__ __launch_bounds__(512, 1)
void scan_kernel(const float* __restrict__ P, const float* __restrict__ Gb,
                 const float* __restrict__ rewards, const float* __restrict__ n_g,
                 int* __restrict__ state, u64* __restrict__ decs) {
  __shared__ float corr0[CORR_SZ];
  __shared__ float corr1[CORR_SZ];
  __shared__ float grow[8][B_ITEMS];   // G-row ring (8 KB)
  __shared__ float rew_l[B_ITEMS];
  __shared__ u64 partials[2][8];
  const int t = threadIdx.x;          // 0..511
  const int lane = t & 63, wave = t >> 6;
  const int s_base = t << 3;
  const int c_base = s_base + (t >> 1);  // SWZ(s_base+k) == c_base + k, k<8

  int num = state[0];
  int ptr = state[1];

  for (int s = t; s < CORR_SZ; s += 512) { corr0[s] = 0.f; corr1[s] = 0.f; }
  if (t < B_ITEMS) {
    rew_l[t] = rewards[t];
    grow[0][t] = Gb[t];                     // G row 0
    grow[1][t] = Gb[B_ITEMS + t];           // G row 1
  }
  float pend_a = (t < B_ITEMS) ? Gb[2 * B_ITEMS + t] : 0.f;  // row 2
  float pend_b = (t < B_ITEMS) ? Gb[3 * B_ITEMS + t] : 0.f;  // row 3

  // per-slot ||t_s||^2 in owner registers; +inf marks invalid
  float n_reg[8];
#pragma unroll
  for (int k = 0; k < 8; k += 4) {
    float4 nv = *(const float4*)(n_g + s_base + k);
    n_reg[k + 0] = (s_base + k + 0 < num) ? nv.x : __uint_as_float(0x7F800000u);
    n_reg[k + 1] = (s_base + k + 1 < num) ? nv.y : __uint_as_float(0x7F800000u);
    n_reg[k + 2] = (s_base + k + 2 < num) ? nv.z : __uint_as_float(0x7F800000u);
    n_reg[k + 3] = (s_base + k + 3 < num) ? nv.w : __uint_as_float(0x7F800000u);
  }
  float alpha_r[8];
#pragma unroll
  for (int k = 0; k < 8; k++) alpha_r[k] = 1.f;

  // p_cur = row 0 (fully corrected at loop entry)
  float p_cur[8];
#pragma unroll
  for (int k = 0; k < 8; k += 4) {
    float4 v0 = *(const float4*)(P + s_base + k);
    p_cur[k] = v0.x; p_cur[k + 1] = v0.y; p_cur[k + 2] = v0.z; p_cur[k + 3] = v0.w;
  }

  // raw ping-pong: buffer A holds P row 1 initially
  float raw_a[8], raw_b[8];
  {
    const float* rp = P + (size_t)S_SLOTS + s_base;
#pragma unroll
    for (int k = 0; k < 8; k += 4) {
      float4 v = *(const float4*)(rp + k);
      raw_a[k] = v.x; raw_a[k + 1] = v.y; raw_a[k + 2] = v.z; raw_a[k + 3] = v.w;
    }
#pragma unroll
    for (int k = 0; k < 8; k++) raw_b[k] = 0.f;
  }

  int my_cslot = -1; float my_coeff = 0.f;   // thread t's decision entry (t<256)
  u32 my_slot = 0; float my_lr = 0.f;        // decision latch for decs[]

  __syncthreads();   // prologue LDS (corr zero, grow rows 0/1, rew) visible

#define OWNFIX(K, I) { const float nold = n_reg[K]; \
    if (upd) { \
      n_reg[K] = omr * omr * nold + 2.0f * lr * omr * p_cur[K] + lr * lr * gi_l; \
      alpha_r[K] = __fmul_rn(alpha_r[K], omr); \
      if ((I) + 1 < B_ITEMS) cv[K] = fmaf(omr, cv[K], __fmul_rn(lr, g1)); \
    } else { n_reg[K] = gi_l; alpha_r[K] = 0.f; \
      if ((I) + 1 < B_ITEMS) cv[K] = g1; } }

#define SCAN_STEP(I, CBUF, RAWC, RAWN, PEND) { \
    /* G-row staging: write row I+2 (loaded 2 steps ago), load row I+4 */ \
    if (t < B_ITEMS) { \
      if ((I) + 2 < B_ITEMS) grow[((I) + 2) & 7][t] = PEND; \
      if ((I) + 4 < B_ITEMS) PEND = Gb[(size_t)((I) + 4) * B_ITEMS + t]; \
    } \
    /* prefetch raw P row I+2 */ \
    if ((I) + 2 < B_ITEMS) { \
      const float* rp = P + (size_t)((I) + 2) * S_SLOTS + s_base; \
      _Pragma("unroll") \
      for (int k = 0; k < 8; k += 4) { \
        float4 v = *(const float4*)(rp + k); \
        RAWN[k] = v.x; RAWN[k + 1] = v.y; RAWN[k + 2] = v.z; RAWN[k + 3] = v.w; \
      } \
    } \
    /* uniform LDS broadcast reads (early; consumed post-barrier) */ \
    const float gi_l = grow[(I) & 7][(I)]; \
    const float riv = rew_l[(I)]; \
    float g1 = 0.f; \
    if ((I) + 1 < B_ITEMS) g1 = grow[(I) & 7][(I) + 1]; \
    /* SCATTER for entering row I+1 (coeffs S_{I-1}); G[I+1][t] via LDS */ \
    if ((I) + 1 < B_ITEMS && my_coeff != 0.f) \
      atomicAdd(&CBUF[SWZ(my_cslot)], \
                __fmul_rn(my_coeff, grow[((I) + 1) & 7][t])); \
    /* KEYS: f32 d2 per owned slot; local min + lowest-index resolve */ \
    float d2[8]; \
    _Pragma("unroll") \
    for (int k = 0; k < 8; k++) { \
      const float v = fmaf(-2.0f, p_cur[k], n_reg[k] + gi_l); \
      d2[k] = (v > 0.f) ? v : 0.f; \
    } \
    float dloc = d2[0]; \
    _Pragma("unroll") \
    for (int k = 1; k < 8; k++) dloc = fminf(dloc, d2[k]); \
    u32 iloc = 0; \
    _Pragma("unroll") \
    for (int k = 7; k >= 1; k--) if (d2[k] == dloc) iloc = (u32)k; \
    const u32 sloc = (u32)s_base + iloc; \
    /* wave min via DPP + ballot (lowest lane, exact tie-break) */ \
    const float dmin = wave_min_f32(dloc); \
    const u64 bmask = __ballot(dloc == dmin); \
    const int bl = __ffsll((unsigned long long)bmask) - 1; \
    const u32 swave = (u32)__builtin_amdgcn_readlane((int)sloc, bl); \
    if (lane == 0) \
      partials[(I) & 1][wave] = ((u64)__float_as_uint(dmin) << 32) | swave; \
    asm volatile("s_waitcnt lgkmcnt(0)" ::: "memory"); \
    __builtin_amdgcn_s_barrier(); \
    __builtin_amdgcn_sched_barrier(0); \
    /* DEC: redundant decision; read own corr slice */ \
    u64 bk = partials[(I) & 1][0]; \
    { u64 v = partials[(I) & 1][1]; if (v < bk) bk = v; \
      v = partials[(I) & 1][2]; if (v < bk) bk = v; \
      v = partials[(I) & 1][3]; if (v < bk) bk = v; \
      v = partials[(I) & 1][4]; if (v < bk) bk = v; \
      v = partials[(I) & 1][5]; if (v < bk) bk = v; \
      v = partials[(I) & 1][6]; if (v < bk) bk = v; \
      v = partials[(I) & 1][7]; if (v < bk) bk = v; } \
    float cv[8]; \
    if ((I) + 1 < B_ITEMS) { \
      _Pragma("unroll") \
      for (int k = 0; k < 8; k++) cv[k] = CBUF[c_base + k]; \
    } else { \
      _Pragma("unroll") \
      for (int k = 0; k < 8; k++) cv[k] = 0.f; \
    } \
    const float d2b = __uint_as_float((u32)(bk >> 32)); \
    const int nslot = (int)(u32)bk; \
    const bool upd = (num > 0) && (d2b < 4.0f); \
    const float lr = __fmul_rn(0.01f, __fadd_rn(1.0f, fabsf(riv))); \
    const int slot = upd ? nslot : ptr; \
    const float omr = 1.0f - lr; \
    if (!upd) { num = min(num + 1, S_SLOTS); ptr = (ptr + 1) & (S_SLOTS - 1); } \
    if ((I) == t) { my_slot = (u32)slot | (upd ? 0x80000000u : 0u); my_lr = lr; } \
    if (my_cslot == slot) my_coeff = upd ? __fmul_rn(my_coeff, omr) : 0.f; \
    if ((I) == t) { my_cslot = slot; my_coeff = upd ? lr : 1.f; } \
    /* owner: n/alpha recurrence + cv fix for decision I */ \
    if ((slot >> 3) == t) { \
      switch (slot & 7) { \
        case 0:  OWNFIX(0, I) break; case 1:  OWNFIX(1, I) break; \
        case 2:  OWNFIX(2, I) break; case 3:  OWNFIX(3, I) break; \
        case 4:  OWNFIX(4, I) break; case 5:  OWNFIX(5, I) break; \
        case 6:  OWNFIX(6, I) break; default: OWNFIX(7, I) break; \
      } \
    } \
    /* ENTER row I+1: p_cur = alpha*raw + cv; zero own corr entries */ \
    if ((I) + 1 < B_ITEMS) { \
      _Pragma("unroll") \
      for (int k = 0; k < 8; k++) { \
        p_cur[k] = fmaf(alpha_r[k], RAWC[k], cv[k]); \
        CBUF[c_base + k] = 0.f; \
      } \
    } \
  }

  for (int i = 0; i < B_ITEMS; i += 2) {
    SCAN_STEP(i,     corr0, raw_a, raw_b, pend_a)
    SCAN_STEP(i + 1, corr1, raw_b, raw_a, pend_b)
  }
#undef SCAN_STEP
#undef OWNFIX

  if (t == 0) { state[0] = num; state[1] = ptr; }
  if (t < B_ITEMS)
    decs[t] = ((u64)__float_as_uint(my_lr) << 32) | (u64)my_slot;
}

// ---------------------------------------------------------------------------
// apply: materialize the block's trace mutations. WG j owns slot_j iff step j
// is the LAST step touching it. Composition: t = alpha*t_snap + sum beta_j c_j.
// Recomputes exact ||t||^2 -> n_g (bounds numeric drift to one block).
// ---------------------------------------------------------------------------
__global__ __launch_bounds__(256)
void apply_kernel(const float* __restrict__ content,  // block 256 x 1024
                  const u64* __restrict__ decs,       // 256 decisions
                  float* __restrict__ traces,         // = out
                  float* __restrict__ n_g) {
  __shared__ u32 aslot[B_ITEMS];
  __shared__ float alr[B_ITEMS];
  __shared__ float betas[B_ITEMS];
  __shared__ int notowner;
  __shared__ float wsum[4];
  const int t = threadIdx.x, j = blockIdx.x;
  const int lane = t & 63, wave = t >> 6;
  const u64 d = decs[t];
  aslot[t] = (u32)(d & 0xFFFFFFFFull);
  alr[t] = __uint_as_float((u32)(d >> 32));
  if (t == 0) notowner = 0;
  __syncthreads();
  const u32 myslot = aslot[j] & 0x7FFFFFFFu;
  if (t > j && (aslot[t] & 0x7FFFFFFFu) == myslot) notowner = 1;
  __syncthreads();
  if (notowner) return;

  float alpha = 1.f, beta = 0.f;
  for (int k = 0; k < B_ITEMS; k++) {
    const u32 a = aslot[k];
    if ((a & 0x7FFFFFFFu) == myslot) {
      const float lr = alr[k];
      if (a & 0x80000000u) {           // update
        const float om = 1.f - lr;
        alpha *= om; beta *= om;
        if (t == k) beta += lr;
      } else {                         // insert
        alpha = 0.f; beta = (t == k) ? 1.f : 0.f;
      }
    }
  }
  betas[t] = beta;
  __syncthreads();

  float4 v = *(const float4*)(traces + (size_t)myslot * D_SEM + 4 * t);
  v.x *= alpha; v.y *= alpha; v.z *= alpha; v.w *= alpha;
  for (int k = 0; k < B_ITEMS; k++) {
    if ((aslot[k] & 0x7FFFFFFFu) == myslot) {
      const float bk = betas[k];
      const float4 c = *(const float4*)(content + (size_t)k * D_SEM + 4 * t);
      v.x = fmaf(bk, c.x, v.x); v.y = fmaf(bk, c.y, v.y);
      v.z = fmaf(bk, c.z, v.z); v.w = fmaf(bk, c.w, v.w);
    }
  }
  *(float4*)(traces + (size_t)myslot * D_SEM + 4 * t) = v;
  float nn = v.x * v.x + v.y * v.y + v.z * v.z + v.w * v.w;
#pragma unroll
  for (int o = 32; o; o >>= 1) nn += __shfl_down(nn, o, 64);
  if (lane == 0) wsum[wave] = nn;
  __syncthreads();
  if (t == 0) n_g[myslot] = wsum[0] + wsum[1] + wsum[2] + wsum[3];
}

// ---------------------------------------------------------------------------
// finalize: parallel strengths replay via two-pass LDS histogram.
// Per slot: final strength = 1 + (#updates after last insert) if ever
// inserted, else strengths0 + #updates.  Then masked mean + scalars.
// ---------------------------------------------------------------------------
__global__ __launch_bounds__(256)
void finalize_kernel(const float* __restrict__ strengths0,
                     const u64* __restrict__ decs,
                     const int* __restrict__ state, float* __restrict__ out) {
  __shared__ int last_ins[S_SLOTS];
  __shared__ int cnt[S_SLOTS];
  __shared__ float wsum[4];
  const int t = threadIdx.x, lane = t & 63, wave = t >> 6;
  for (int s = t; s < S_SLOTS; s += 256) { last_ins[s] = -1; cnt[s] = 0; }
  __syncthreads();
  // pass 1: last insert index per slot
  for (int k = t; k < N_ITEMS; k += 256) {
    const u32 dd = (u32)(decs[k] & 0xFFFFFFFFull);
    if (!(dd & 0x80000000u)) atomicMax(&last_ins[(int)dd], k);
  }
  __syncthreads();
  // pass 2: count updates after the last insert
  for (int k = t; k < N_ITEMS; k += 256) {
    const u32 dd = (u32)(decs[k] & 0xFFFFFFFFull);
    const int slot = (int)(dd & 0x7FFFFFFFu);
    if ((dd & 0x80000000u) && k > last_ins[slot]) atomicAdd(&cnt[slot], 1);
  }
  __syncthreads();
  const int num = state[0];
  float* outs = out + (size_t)S_SLOTS * D_SEM;
  float lsum = 0.f;
  for (int s = t; s < S_SLOTS; s += 256) {
    const float base = (last_ins[s] >= 0) ? 1.f : strengths0[s];
    const float v = base + (float)cnt[s];
    outs[s] = v;
    if (s < num) lsum += v;
  }
#pragma unroll
  for (int o = 32; o; o >>= 1) lsum += __shfl_down(lsum, o, 64);
  if (lane == 0) wsum[wave] = lsum;
  __syncthreads();
  if (t == 0) {
    const float total = wsum[0] + wsum[1] + wsum[2] + wsum[3];
    float denom = (float)num;
    if (denom < 1.f) denom = 1.f;
    outs[S_SLOTS + 0] = (float)num;
    outs[S_SLOTS + 1] = (float)N_ITEMS;
    outs[S_SLOTS + 2] = (num > 0) ? (total / denom) : 0.f;
  }
}

// ---------------------------------------------------------------------------
extern "C" void kernel_launch(void* const* d_in, const int* in_sizes, int n_in,
                              void* d_out, int out_size, void* d_ws, size_t ws_size,
                              hipStream_t stream) {
  const float* states  = (const float*)d_in[0];
  const float* rewards = (const float*)d_in[1];
  const float* W       = (const float*)d_in[2];
  const float* bias    = (const float*)d_in[3];
  const float* traces0 = (const float*)d_in[4];
  const float* str0    = (const float*)d_in[5];
  float* out = (float*)d_out;   // traces live here (working + final)

  // ws layout (~24.5 MB): content chunk 16MB | P 4MB | Gram 4MB | n_g | decs | state
  char* p = (char*)d_ws;
  float* cbuf = (float*)p;                 p += (size_t)CHUNK_ITEMS * D_SEM * 4;
  float* P    = (float*)p;                 p += (size_t)B_ITEMS * S_SLOTS * 4;
  float* Gb   = (float*)p;                 p += (size_t)CHUNK_BLKS * B_ITEMS * B_ITEMS * 4;
  float* n_g  = (float*)p;                 p += (size_t)S_SLOTS * 4;
  u64*   decs = (u64*)p;                   p += (size_t)N_ITEMS * 8;
  int*   state = (int*)p;

  init_kernel<<<S_SLOTS, 256, 0, stream>>>(traces0, out, n_g, state);

  for (int c = 0; c < N_ITEMS / CHUNK_ITEMS; c++) {
    gemm_kernel<<<dim3(CHUNK_ITEMS / 64, D_SEM / 64), 256, 0, stream>>>(
        states + (size_t)c * CHUNK_ITEMS * D_STATE, W, bias, cbuf);
    gram_kernel<<<dim3(4, 4, CHUNK_BLKS), 256, 0, stream>>>(cbuf, Gb);
    for (int bb = 0; bb < CHUNK_BLKS; bb++) {
      const int b = c * CHUNK_BLKS + bb;
      const float* cblk = cbuf + (size_t)bb * B_ITEMS * D_SEM;
      const float* Gblk = Gb + (size_t)bb * B_ITEMS * B_ITEMS;
      pgemm_kernel<<<dim3(4, S_SLOTS / 64), 256, 0, stream>>>(cblk, out, P, state);
      scan_kernel<<<1, 512, 0, stream>>>(P, Gblk, rewards + (size_t)b * B_ITEMS,
                                         n_g, state, decs + (size_t)b * B_ITEMS);
      apply_kernel<<<B_ITEMS, 256, 0, stream>>>(cblk, decs + (size_t)b * B_ITEMS,
                                                out, n_g);
    }
  }
  finalize_kernel<<<1, 256, 0, stream>>>(str0, decs, state, out);
}